// Round 11
// baseline (470.193 us; speedup 1.0000x reference)
//
#include <hip/hip_runtime.h>

#define BB     4
#define NQS    4096
#define NVS    9216
#define E_DIM  768
#define NHEAD  8
#define NPTS   4
#define HDIM   96
#define HFEAT  96
#define WFEAT  96
#define MQR    16384   // BB*NQS

typedef __attribute__((ext_vector_type(8))) short  s8v;    // 8 x bf16 (4 VGPRs)
typedef __attribute__((ext_vector_type(4))) short  s4v;    // 4 x bf16
typedef __attribute__((ext_vector_type(4))) float  f4v;    // MFMA acc

__device__ __forceinline__ unsigned short f2bf(float x) {
    unsigned int u = __builtin_bit_cast(unsigned int, x);
    unsigned int r = (u + 0x7fffu + ((u >> 16) & 1u)) >> 16;
    return (unsigned short)r;
}
__device__ __forceinline__ float bf2f(unsigned short s) {
    unsigned int u = ((unsigned int)s) << 16;
    return __builtin_bit_cast(float, u);
}
__device__ __forceinline__ float bf2f_s(short s) {
    return bf2f((unsigned short)s);
}

#define GLD16(gp, lp) \
    __builtin_amdgcn_global_load_lds( \
        (__attribute__((address_space(1))) void*)(gp), \
        (__attribute__((address_space(3))) void*)(lp), 16, 0, 0)

// ---------------------------------------------------------------------------
// Fused LayerNorm + bf16 cast v2: ONE WAVE PER ROW (64 lanes x 12 floats),
// pure-shuffle reduce, no LDS, no barriers. 4 rows per 256-thread block.
// Handles query rows [0, MQR) and feat rows [MQR, MQR+MV) in one launch.
// ---------------------------------------------------------------------------
__global__ __launch_bounds__(256) void ln_fused_kernel(
    const float* __restrict__ q, const float* __restrict__ f,
    const float* __restrict__ qw, const float* __restrict__ qb,
    const float* __restrict__ fw, const float* __restrict__ fb,
    unsigned short* __restrict__ qout, unsigned short* __restrict__ fout,
    float* __restrict__ stats) {
    const int wv = threadIdx.x >> 6, lane = threadIdx.x & 63;
    const int row = blockIdx.x * 4 + wv;
    const bool isq = row < MQR;
    const float* x = isq ? (q + (size_t)row * E_DIM)
                         : (f + (size_t)(row - MQR) * E_DIM);
    const float4 v0 = ((const float4*)x)[lane];
    const float4 v1 = ((const float4*)x)[lane + 64];
    const float4 v2 = ((const float4*)x)[lane + 128];
    float s1 = v0.x + v0.y + v0.z + v0.w + v1.x + v1.y + v1.z + v1.w
             + v2.x + v2.y + v2.z + v2.w;
    float s2 = v0.x * v0.x + v0.y * v0.y + v0.z * v0.z + v0.w * v0.w
             + v1.x * v1.x + v1.y * v1.y + v1.z * v1.z + v1.w * v1.w
             + v2.x * v2.x + v2.y * v2.y + v2.z * v2.z + v2.w * v2.w;
    #pragma unroll
    for (int o = 32; o > 0; o >>= 1) {
        s1 += __shfl_down(s1, o, 64);
        s2 += __shfl_down(s2, o, 64);
    }
    const float mean = __shfl(s1, 0, 64) * (1.0f / E_DIM);
    const float m2   = __shfl(s2, 0, 64) * (1.0f / E_DIM);
    const float rstd = rsqrtf(m2 - mean * mean + 1e-6f);
    if (isq && lane == 0) { stats[row * 2] = mean; stats[row * 2 + 1] = rstd; }

    const float* w = isq ? qw : fw;
    const float* b = isq ? qb : fb;
    unsigned short* o = isq ? (qout + (size_t)row * E_DIM)
                            : (fout + (size_t)(row - MQR) * E_DIM);
    const float4 vv[3] = {v0, v1, v2};
    #pragma unroll
    for (int c = 0; c < 3; c++) {
        const float4 w4 = ((const float4*)w)[lane + c * 64];
        const float4 b4 = ((const float4*)b)[lane + c * 64];
        s4v ov;
        ov[0] = (short)f2bf((vv[c].x - mean) * rstd * w4.x + b4.x);
        ov[1] = (short)f2bf((vv[c].y - mean) * rstd * w4.y + b4.y);
        ov[2] = (short)f2bf((vv[c].z - mean) * rstd * w4.z + b4.z);
        ov[3] = (short)f2bf((vv[c].w - mean) * rstd * w4.w + b4.w);
        ((s4v*)o)[lane + c * 64] = ov;
    }
}

// ---------------------------------------------------------------------------
// 32x32 LDS tile transpose + bf16 cast, both weights in one launch (z=0/1).
// ---------------------------------------------------------------------------
__global__ void transpose_cast2_kernel(const float* __restrict__ W0, const float* __restrict__ W1,
                                       unsigned short* __restrict__ T0, unsigned short* __restrict__ T1) {
    __shared__ float tile[32][33];
    const float* W = blockIdx.z ? W1 : W0;
    unsigned short* Wt = blockIdx.z ? T1 : T0;
    const int bi = blockIdx.y * 32, bj = blockIdx.x * 32;
    const int t = threadIdx.x;
    const int r = t >> 5, c = t & 31;
    #pragma unroll
    for (int i = 0; i < 4; i++)
        tile[r + i * 8][c] = W[(size_t)(bi + r + i * 8) * E_DIM + bj + c];
    __syncthreads();
    #pragma unroll
    for (int i = 0; i < 4; i++)
        Wt[(size_t)(bj + r + i * 8) * E_DIM + bi + c] = f2bf(tile[c][r + i * 8]);
}

// ---------------------------------------------------------------------------
// Concatenated + transposed + zero-padded query-proj weights (off|attn|pad)
// ---------------------------------------------------------------------------
__global__ void build_wqc_kernel(const float* __restrict__ W_off, const float* __restrict__ W_attn,
                                 const float* __restrict__ b_off, const float* __restrict__ b_attn,
                                 unsigned short* __restrict__ Wt, float* __restrict__ bcat) {
    const int idx = blockIdx.x * 256 + threadIdx.x;  // 128*768 total
    const int rrow = idx / E_DIM, k = idx % E_DIM;
    float v = 0.f;
    if (rrow < 64) v = W_off[(size_t)k * 64 + rrow];
    else if (rrow < 96) v = W_attn[(size_t)k * 32 + (rrow - 64)];
    Wt[idx] = f2bf(v);
    if (idx < 128) {
        float b = 0.f;
        if (idx < 64) b = b_off[idx];
        else if (idx < 96) b = b_attn[idx - 64];
        bcat[idx] = b;
    }
}

// ---------------------------------------------------------------------------
// 128x128 NT-GEMM (round-1 verified structure). EPI: 1 = fp32 out + bias;
// 2 = fp32 fused final residual (r1-measured epilogue order: ti,tj,r).
// ---------------------------------------------------------------------------
template <int EPI>
__global__ __launch_bounds__(256, 3) void mfma_gemm128(
    const unsigned short* __restrict__ A, const unsigned short* __restrict__ Bt,
    const float* __restrict__ bias, void* __restrict__ C, int ldC,
    const float* __restrict__ query, const float* __restrict__ qstats,
    const float* __restrict__ lnw, const float* __restrict__ lnb,
    const float* __restrict__ gamma) {
    __shared__ unsigned short As[128 * 64];   // [kseg 0..7][row 0..127][8]
    __shared__ unsigned short Bs[128 * 64];

    constexpr int K = E_DIM;
    const int tid = threadIdx.x;
    const int wave = tid >> 6;
    const int lane = tid & 63;
    const int quad = lane >> 4;
    const int l16 = lane & 15;

    const int nwg = gridDim.x * gridDim.y;
    const int flat = blockIdx.y * gridDim.x + blockIdx.x;
    const int cpx = nwg >> 3;
    const int swz = (flat & 7) * cpx + (flat >> 3);
    const int bx = swz % gridDim.x;
    const int by = swz / gridDim.x;
    const int bm = by * 128;
    const int bn = bx * 128;
    const int wrow = wave >> 1, wcol = wave & 1;

    const unsigned short* arow[4];
    const unsigned short* brow[4];
    unsigned short* aldst[4];
    unsigned short* bldst[4];
    #pragma unroll
    for (int i = 0; i < 4; i++) {
        const int chunk = wave * 4 + i;
        const int s = chunk >> 1, r = (chunk & 1) * 64 + lane;
        arow[i] = A + (size_t)(bm + r) * K + s * 8;
        brow[i] = Bt + (size_t)(bn + r) * K + s * 8;
        aldst[i] = As + chunk * 512;
        bldst[i] = Bs + chunk * 512;
    }

    f4v acc[4][4] = {};

    for (int k0 = 0; k0 < K; k0 += 64) {
        #pragma unroll
        for (int i = 0; i < 4; i++)
            GLD16(arow[i] + k0, aldst[i]);
        #pragma unroll
        for (int i = 0; i < 4; i++)
            GLD16(brow[i] + k0, bldst[i]);

        __syncthreads();

        #pragma unroll
        for (int c = 0; c < 2; c++) {
            s8v af[4], bf[4];
            #pragma unroll
            for (int ti = 0; ti < 4; ti++)
                af[ti] = *(const s8v*)(As + ((size_t)((c * 4 + quad) * 128 + wrow * 64 + ti * 16 + l16)) * 8);
            #pragma unroll
            for (int tj = 0; tj < 4; tj++)
                bf[tj] = *(const s8v*)(Bs + ((size_t)((c * 4 + quad) * 128 + wcol * 64 + tj * 16 + l16)) * 8);
            #pragma unroll
            for (int ti = 0; ti < 4; ti++)
                #pragma unroll
                for (int tj = 0; tj < 4; tj++)
                    acc[ti][tj] = __builtin_amdgcn_mfma_f32_16x16x32_bf16(af[ti], bf[tj], acc[ti][tj], 0, 0, 0);
        }
        __syncthreads();
    }

    #pragma unroll
    for (int ti = 0; ti < 4; ti++) {
        const int gm_base = bm + wrow * 64 + ti * 16 + quad * 4;
        #pragma unroll
        for (int tj = 0; tj < 4; tj++) {
            const int gn = bn + wcol * 64 + tj * 16 + l16;
            const float bv = bias[gn];
            #pragma unroll
            for (int r = 0; r < 4; r++) {
                const int gm = gm_base + r;
                const float v = acc[ti][tj][r] + bv;
                if (EPI == 1) {
                    ((float*)C)[(size_t)gm * ldC + gn] = v;
                } else {
                    const size_t idx = (size_t)gm * ldC + gn;
                    const float qv = query[idx];
                    const float qln = (qv - qstats[gm * 2]) * qstats[gm * 2 + 1] * lnw[gn] + lnb[gn];
                    ((float*)C)[idx] = qv + gamma[gn] * (qln + v);
                }
            }
        }
    }
}

// ---------------------------------------------------------------------------
// 256x256 8-wave phase-pipelined NT-GEMM (r5 barrier/vmcnt schedule — the
// measured-best variant, reverted verbatim from r9). B fragments read once
// per tile into registers; A fragments 2 ti-groups per phase. Staging
// interleaved per phase; counted vmcnt(2) once per tile; 2 barriers/tile.
// EPI=0 only: bf16 out in (B,H,S,D) layout.
// ---------------------------------------------------------------------------
template <int G>
__device__ __forceinline__ void tigroup(const unsigned short* as_, const s8v (&bfr)[2][4],
                                        f4v (&acc)[8][4], int quad, int l16, int wrow) {
    s8v af[2][2];
    #pragma unroll
    for (int c = 0; c < 2; c++)
        #pragma unroll
        for (int m = 0; m < 2; m++)
            af[c][m] = *(const s8v*)(as_ + ((size_t)((c * 4 + quad) * 256 + wrow * 128 + (G * 2 + m) * 16 + l16)) * 8);
    #pragma unroll
    for (int c = 0; c < 2; c++)
        #pragma unroll
        for (int m = 0; m < 2; m++)
            #pragma unroll
            for (int n = 0; n < 4; n++)
                acc[G * 2 + m][n] = __builtin_amdgcn_mfma_f32_16x16x32_bf16(
                    af[c][m], bfr[c][n], acc[G * 2 + m][n], 0, 0, 0);
}

__global__ __launch_bounds__(512, 2) void mfma_gemm256(
    const unsigned short* __restrict__ A, const unsigned short* __restrict__ Bt,
    const float* __restrict__ bias, unsigned short* __restrict__ C) {
    __shared__ unsigned short As[2][256 * 64];
    __shared__ unsigned short Bs[2][256 * 64];

    constexpr int K = E_DIM;
    constexpr int NT = K / 64;                 // 12 K-tiles
    const int tid = threadIdx.x;
    const int wave = tid >> 6;                 // 0..7
    const int lane = tid & 63;
    const int quad = lane >> 4;
    const int l16 = lane & 15;

    // XCD-aware bijective swizzle (nwg % 8 == 0: 432)
    const int nwg = gridDim.x * gridDim.y;
    const int flat = blockIdx.y * gridDim.x + blockIdx.x;
    const int cpx = nwg >> 3;
    const int swz = (flat & 7) * cpx + (flat >> 3);
    const int bx = swz % gridDim.x;
    const int by = swz / gridDim.x;
    const int bm = by * 256;
    const int bn = bx * 256;
    const int wrow = wave >> 2;                // 0..1
    const int wcol = wave & 3;                 // 0..3

    const unsigned short* gsrc[4][2];
    int ldst[4][2];
    #pragma unroll
    for (int h = 0; h < 4; h++) {
        #pragma unroll
        for (int i = 0; i < 2; i++) {
            const int ch = wave * 2 + i;
            const int s = ch >> 1, rsub = ch & 1;
            const int rw = (h & 1) * 128 + rsub * 64 + lane;   // row/col in [0,256)
            const unsigned short* base = (h < 2) ? (A + (size_t)(bm + rw) * K)
                                                 : (Bt + (size_t)(bn + rw) * K);
            gsrc[h][i] = base + s * 8;
            ldst[h][i] = (s * 256 + rw) * 8;
        }
    }

    #define STAGE256(h, kt, buf) do { \
        unsigned short* lb_ = ((h) < 2 ? &As[(buf)][0] : &Bs[(buf)][0]); \
        GLD16(gsrc[h][0] + (size_t)(kt) * 64, lb_ + ldst[h][0]); \
        GLD16(gsrc[h][1] + (size_t)(kt) * 64, lb_ + ldst[h][1]); \
    } while (0)

    f4v acc[8][4] = {};

    // prologue: tile 0 -> buf 0 (8 loads)
    #pragma unroll
    for (int h = 0; h < 4; h++) STAGE256(h, 0, 0);

    int cur = 0;
    for (int t = 0; t < NT; ++t) {
        const unsigned short* as_ = &As[cur][0];
        const unsigned short* bs_ = &Bs[cur][0];
        const int nb = cur ^ 1;
        const bool pf = (t + 1 < NT);

        // ---- phase 0: prefetch H0(t+1); wait prev tile landed (counted) ----
        if (pf) {
            STAGE256(0, t + 1, nb);
            asm volatile("s_waitcnt vmcnt(2)" ::: "memory");
        } else {
            asm volatile("s_waitcnt vmcnt(0)" ::: "memory");
        }
        __builtin_amdgcn_s_barrier();              // all waves' tile-t loads landed
        __builtin_amdgcn_sched_barrier(0);

        // read ALL B fragments once per tile into registers (8 x b128)
        s8v bfr[2][4];
        #pragma unroll
        for (int c = 0; c < 2; c++)
            #pragma unroll
            for (int n = 0; n < 4; n++)
                bfr[c][n] = *(const s8v*)(bs_ + ((size_t)((c * 4 + quad) * 256 + wcol * 64 + n * 16 + l16)) * 8);

        __builtin_amdgcn_s_setprio(1);
        tigroup<0>(as_, bfr, acc, quad, l16, wrow);
        __builtin_amdgcn_s_setprio(0);

        // ---- phase 1 ----
        if (pf) STAGE256(1, t + 1, nb);
        __builtin_amdgcn_s_setprio(1);
        tigroup<1>(as_, bfr, acc, quad, l16, wrow);
        __builtin_amdgcn_s_setprio(0);

        // ---- phase 2 ----
        if (pf) STAGE256(2, t + 1, nb);
        __builtin_amdgcn_s_setprio(1);
        tigroup<2>(as_, bfr, acc, quad, l16, wrow);
        __builtin_amdgcn_s_setprio(0);

        // ---- phase 3: A-reads, end-of-tile barrier, then MFMA ----
        if (pf) STAGE256(3, t + 1, nb);
        s8v af3[2][2];
        #pragma unroll
        for (int c = 0; c < 2; c++)
            #pragma unroll
            for (int m = 0; m < 2; m++)
                af3[c][m] = *(const s8v*)(as_ + ((size_t)((c * 4 + quad) * 256 + wrow * 128 + (6 + m) * 16 + l16)) * 8);
        asm volatile("s_waitcnt lgkmcnt(0)" ::: "memory");
        __builtin_amdgcn_sched_barrier(0);
        __builtin_amdgcn_s_barrier();              // all waves done reading buf cur
        __builtin_amdgcn_sched_barrier(0);
        __builtin_amdgcn_s_setprio(1);
        #pragma unroll
        for (int c = 0; c < 2; c++)
            #pragma unroll
            for (int m = 0; m < 2; m++)
                #pragma unroll
                for (int n = 0; n < 4; n++)
                    acc[6 + m][n] = __builtin_amdgcn_mfma_f32_16x16x32_bf16(
                        af3[c][m], bfr[c][n], acc[6 + m][n], 0, 0, 0);
        __builtin_amdgcn_s_setprio(0);

        cur ^= 1;
    }
    #undef STAGE256

    // ---- epilogue (r5 order: ti outer, tj, r inner) ----
    #pragma unroll
    for (int ti = 0; ti < 8; ti++) {
        const int gm_base = bm + wrow * 128 + ti * 16 + quad * 4;
        #pragma unroll
        for (int tj = 0; tj < 4; tj++) {
            const int gn = bn + wcol * 64 + tj * 16 + l16;
            const float bv = bias[gn];
            const int hh = gn / HDIM, dd = gn - hh * HDIM;
            #pragma unroll
            for (int r = 0; r < 4; r++) {
                const int gm = gm_base + r;
                const float v = acc[ti][tj][r] + bv;
                const int b = gm / NVS, s = gm - b * NVS;
                const size_t vidx = (((size_t)b * NHEAD + hh) * NVS + s) * HDIM + dd;
                C[vidx] = f2bf(v);
            }
        }
    }
}

// ---------------------------------------------------------------------------
// MSDA core: grid (8 heads, 512); block 384 = 32 rows x 12 lanes.
// Preamble spread over 128 threads (one (row, point) each; 4-lane shuffle
// softmax) — r10-measured ~21 µs better than the 32-thread serial form.
// ---------------------------------------------------------------------------
__global__ __launch_bounds__(384) void msda_kernel(
    const unsigned short* __restrict__ value,  // (B, 8, 9216, 96) bf16
    const float* __restrict__ oa,              // (B*NQ, 128): 0-63 off, 64-95 attn
    const float* __restrict__ refp,            // (B*NQ, 2)
    unsigned short* __restrict__ out) {        // (B*NQ, 768) bf16
    const int h = blockIdx.x;
    const int row0 = blockIdx.y * 32;
    const int t = threadIdx.x;

    __shared__ float x_s[128], y_s[128], aw_s[128];
    if (t < 128) {
        const int r = t >> 2, p = t & 3;       // 4-lane group per row (aligned)
        const int row = row0 + r;
        const float* oar = oa + (size_t)row * 128;
        float a = oar[64 + h * 4 + p];
        float mx = fmaxf(a, __shfl_xor(a, 1, 64));
        mx = fmaxf(mx, __shfl_xor(mx, 2, 64));
        float e = __expf(a - mx);
        float sden = e + __shfl_xor(e, 1, 64);
        sden += __shfl_xor(sden, 2, 64);
        aw_s[t] = e / sden;
        const float rx = refp[(size_t)row * 2 + 0] * WFEAT - 0.5f;
        const float ry = refp[(size_t)row * 2 + 1] * HFEAT - 0.5f;
        x_s[t] = rx + oar[h * 8 + p * 2 + 0];
        y_s[t] = ry + oar[h * 8 + p * 2 + 1];
    }
    __syncthreads();

    const int r = t / 12;              // 0..31
    const int j = t - r * 12;          // 0..11
    const int row = row0 + r;
    const int b = row >> 12;           // / NQS
    const unsigned short* vb = value + ((size_t)(b * NHEAD + h) * NVS) * HDIM + j * 8;

    float acc[8] = {};
    #pragma unroll
    for (int p = 0; p < 4; p++) {
        const float x = x_s[r * 4 + p];
        const float y = y_s[r * 4 + p];
        const float aw = aw_s[r * 4 + p];
        const float x0f = floorf(x), y0f = floorf(y);
        const float fx = x - x0f, fy = y - y0f;
        const int ix0 = (int)x0f, iy0 = (int)y0f;
        const int ix1 = ix0 + 1, iy1 = iy0 + 1;
        const float wx0 = (ix0 >= 0 && ix0 < WFEAT) ? (1.f - fx) : 0.f;
        const float wx1 = (ix1 >= 0 && ix1 < WFEAT) ? fx : 0.f;
        const float wy0 = (iy0 >= 0 && iy0 < HFEAT) ? (1.f - fy) : 0.f;
        const float wy1 = (iy1 >= 0 && iy1 < HFEAT) ? fy : 0.f;
        const int cx0 = min(max(ix0, 0), WFEAT - 1);
        const int cx1 = min(max(ix1, 0), WFEAT - 1);
        const int cy0 = min(max(iy0, 0), HFEAT - 1);
        const int cy1 = min(max(iy1, 0), HFEAT - 1);
        const float w00 = aw * wy0 * wx0, w01 = aw * wy0 * wx1;
        const float w10 = aw * wy1 * wx0, w11 = aw * wy1 * wx1;
        const s8v v00 = *(const s8v*)(vb + (size_t)(cy0 * WFEAT + cx0) * HDIM);
        const s8v v01 = *(const s8v*)(vb + (size_t)(cy0 * WFEAT + cx1) * HDIM);
        const s8v v10 = *(const s8v*)(vb + (size_t)(cy1 * WFEAT + cx0) * HDIM);
        const s8v v11 = *(const s8v*)(vb + (size_t)(cy1 * WFEAT + cx1) * HDIM);
        #pragma unroll
        for (int k = 0; k < 8; k++) {
            acc[k] += w00 * bf2f_s(v00[k]) + w01 * bf2f_s(v01[k])
                    + w10 * bf2f_s(v10[k]) + w11 * bf2f_s(v11[k]);
        }
    }

    s8v o;
    #pragma unroll
    for (int k = 0; k < 8; k++) o[k] = (short)f2bf(acc[k]);
    *(s8v*)(out + (size_t)row * E_DIM + h * HDIM + j * 8) = o;
}

// ---------------------------------------------------------------------------
extern "C" void kernel_launch(void* const* d_in, const int* in_sizes, int n_in,
                              void* d_out, int out_size, void* d_ws, size_t ws_size,
                              hipStream_t stream) {
    (void)in_sizes; (void)n_in; (void)out_size; (void)ws_size;

    const float* query  = (const float*)d_in[0];
    const float* refp   = (const float*)d_in[1];
    const float* feat   = (const float*)d_in[2];
    const float* ln_q_w = (const float*)d_in[5];
    const float* ln_q_b = (const float*)d_in[6];
    const float* ln_f_w = (const float*)d_in[7];
    const float* ln_f_b = (const float*)d_in[8];
    const float* W_val  = (const float*)d_in[9];
    const float* b_val  = (const float*)d_in[10];
    const float* W_off  = (const float*)d_in[11];
    const float* b_off  = (const float*)d_in[12];
    const float* W_attn = (const float*)d_in[13];
    const float* b_attn = (const float*)d_in[14];
    const float* W_out  = (const float*)d_in[15];
    const float* b_out  = (const float*)d_in[16];
    const float* gamma  = (const float*)d_in[17];
    float* out = (float*)d_out;

    const int MQ = BB * NQS;   // 16384
    const int MV = BB * NVS;   // 36864

    // Workspace layout (bytes)
    char* ws = (char*)d_ws;
    float*          q_stats = (float*)(ws + 0);                   //     131,072
    unsigned short* qbf     = (unsigned short*)(ws + 131072);     //  25,165,824
    unsigned short* fbf     = (unsigned short*)(ws + 25296896);   //  56,623,104
    unsigned short* val_bf  = (unsigned short*)(ws + 81920000);   //  56,623,104 (B,H,S,D)
    unsigned short* msda_bf = (unsigned short*)(ws + 138543104);  //  25,165,824
    float*          offattn = (float*)(ws + 163708928);           //   8,388,608
    unsigned short* Wv_t    = (unsigned short*)(ws + 172097536);  //   1,179,648
    unsigned short* Wo_t    = (unsigned short*)(ws + 173277184);  //   1,179,648
    unsigned short* Wqc_t   = (unsigned short*)(ws + 174456832);  //     196,608
    float*          bcat    = (float*)(ws + 174653440);           //         512

    // 1. LN + bf16 cast (wave-per-row, query+feat fused, no barriers)
    ln_fused_kernel<<<(MQ + MV) / 4, 256, 0, stream>>>(
        query, feat, ln_q_w, ln_q_b, ln_f_w, ln_f_b, qbf, fbf, q_stats);

    // 2. weight prep (both transposes in one launch)
    transpose_cast2_kernel<<<dim3(24, 24, 2), 256, 0, stream>>>(W_val, W_out, Wv_t, Wo_t);
    build_wqc_kernel<<<384, 256, 0, stream>>>(W_off, W_attn, b_off, b_attn, Wqc_t, bcat);

    // 3. value = LN(feat) @ W_value + b_value -> bf16, (B,H,S,D) layout
    mfma_gemm256<<<dim3(E_DIM / 256, MV / 256), 512, 0, stream>>>(
        fbf, Wv_t, b_val, val_bf);

    // 4. offsets|attn = LN(q) @ [W_off|W_attn|0] -> fp32 (16384x128)
    mfma_gemm128<1><<<dim3(1, MQ / 128), 256, 0, stream>>>(
        qbf, Wqc_t, bcat, offattn, 128, nullptr, nullptr, nullptr, nullptr, nullptr);

    // 5. deformable sampling -> bf16 (row-major B*NQ x 768)
    msda_kernel<<<dim3(NHEAD, MQ / 32), 384, 0, stream>>>(val_bf, offattn, refp, msda_bf);

    // 6. out-proj + fused final residual (128^2: 768 blocks = 3/CU)
    mfma_gemm128<2><<<dim3(E_DIM / 128, MQ / 128), 256, 0, stream>>>(
        msda_bf, Wo_t, b_out, out, E_DIM, query, q_stats, ln_q_w, ln_q_b, gamma);
}

// Round 12
// 442.946 us; speedup vs baseline: 1.0615x; 1.0615x over previous
//
#include <hip/hip_runtime.h>

#define BB     4
#define NQS    4096
#define NVS    9216
#define E_DIM  768
#define NHEAD  8
#define NPTS   4
#define HDIM   96
#define HFEAT  96
#define WFEAT  96
#define MQR    16384   // BB*NQS
#define NLNB   13312   // (MQ+MV)/4 ln blocks
#define NTRB   1152    // 24*24*2 transpose blocks
#define NVALB  432     // value-gemm blocks (3 x 144)

typedef __attribute__((ext_vector_type(8))) short  s8v;    // 8 x bf16 (4 VGPRs)
typedef __attribute__((ext_vector_type(4))) short  s4v;    // 4 x bf16
typedef __attribute__((ext_vector_type(4))) float  f4v;    // MFMA acc

__device__ __forceinline__ unsigned short f2bf(float x) {
    unsigned int u = __builtin_bit_cast(unsigned int, x);
    unsigned int r = (u + 0x7fffu + ((u >> 16) & 1u)) >> 16;
    return (unsigned short)r;
}
__device__ __forceinline__ float bf2f(unsigned short s) {
    unsigned int u = ((unsigned int)s) << 16;
    return __builtin_bit_cast(float, u);
}
__device__ __forceinline__ float bf2f_s(short s) {
    return bf2f((unsigned short)s);
}

#define GLD16(gp, lp) \
    __builtin_amdgcn_global_load_lds( \
        (__attribute__((address_space(1))) void*)(gp), \
        (__attribute__((address_space(3))) void*)(lp), 16, 0, 0)

// ---------------------------------------------------------------------------
// Fat prep kernel: ln_fused (blocks 0..13311) | weight transpose (next 1152)
// | wqc concat (last 384). 256 threads each; one launch instead of three.
// ---------------------------------------------------------------------------
__global__ __launch_bounds__(256) void prep_kernel(
    const float* __restrict__ q, const float* __restrict__ f,
    const float* __restrict__ qw, const float* __restrict__ qb,
    const float* __restrict__ fw, const float* __restrict__ fb,
    unsigned short* __restrict__ qout, unsigned short* __restrict__ fout,
    float* __restrict__ stats,
    const float* __restrict__ W0, const float* __restrict__ W1,
    unsigned short* __restrict__ T0, unsigned short* __restrict__ T1,
    const float* __restrict__ W_off, const float* __restrict__ W_attn,
    const float* __restrict__ b_off, const float* __restrict__ b_attn,
    unsigned short* __restrict__ Wqc, float* __restrict__ bcat) {
    __shared__ float tile[32][33];
    const int bid = blockIdx.x;

    if (bid < NLNB) {
        // ---- LayerNorm + bf16 cast: one wave per row, shuffle reduce ----
        const int wv = threadIdx.x >> 6, lane = threadIdx.x & 63;
        const int row = bid * 4 + wv;
        const bool isq = row < MQR;
        const float* x = isq ? (q + (size_t)row * E_DIM)
                             : (f + (size_t)(row - MQR) * E_DIM);
        const float4 v0 = ((const float4*)x)[lane];
        const float4 v1 = ((const float4*)x)[lane + 64];
        const float4 v2 = ((const float4*)x)[lane + 128];
        float s1 = v0.x + v0.y + v0.z + v0.w + v1.x + v1.y + v1.z + v1.w
                 + v2.x + v2.y + v2.z + v2.w;
        float s2 = v0.x * v0.x + v0.y * v0.y + v0.z * v0.z + v0.w * v0.w
                 + v1.x * v1.x + v1.y * v1.y + v1.z * v1.z + v1.w * v1.w
                 + v2.x * v2.x + v2.y * v2.y + v2.z * v2.z + v2.w * v2.w;
        #pragma unroll
        for (int o = 32; o > 0; o >>= 1) {
            s1 += __shfl_down(s1, o, 64);
            s2 += __shfl_down(s2, o, 64);
        }
        const float mean = __shfl(s1, 0, 64) * (1.0f / E_DIM);
        const float m2   = __shfl(s2, 0, 64) * (1.0f / E_DIM);
        const float rstd = rsqrtf(m2 - mean * mean + 1e-6f);
        if (isq && lane == 0) { stats[row * 2] = mean; stats[row * 2 + 1] = rstd; }
        const float* w = isq ? qw : fw;
        const float* b = isq ? qb : fb;
        unsigned short* o = isq ? (qout + (size_t)row * E_DIM)
                                : (fout + (size_t)(row - MQR) * E_DIM);
        const float4 vv[3] = {v0, v1, v2};
        #pragma unroll
        for (int c = 0; c < 3; c++) {
            const float4 w4 = ((const float4*)w)[lane + c * 64];
            const float4 b4 = ((const float4*)b)[lane + c * 64];
            s4v ov;
            ov[0] = (short)f2bf((vv[c].x - mean) * rstd * w4.x + b4.x);
            ov[1] = (short)f2bf((vv[c].y - mean) * rstd * w4.y + b4.y);
            ov[2] = (short)f2bf((vv[c].z - mean) * rstd * w4.z + b4.z);
            ov[3] = (short)f2bf((vv[c].w - mean) * rstd * w4.w + b4.w);
            ((s4v*)o)[lane + c * 64] = ov;
        }
    } else if (bid < NLNB + NTRB) {
        // ---- 32x32 transpose + bf16 cast of W_val / W_out ----
        const int idx = bid - NLNB;
        const int z = idx / 576, r2 = idx - z * 576;
        const float* W = z ? W1 : W0;
        unsigned short* Wt = z ? T1 : T0;
        const int bi = (r2 / 24) * 32, bj = (r2 % 24) * 32;
        const int t = threadIdx.x;
        const int r = t >> 5, c = t & 31;
        #pragma unroll
        for (int i = 0; i < 4; i++)
            tile[r + i * 8][c] = W[(size_t)(bi + r + i * 8) * E_DIM + bj + c];
        __syncthreads();
        #pragma unroll
        for (int i = 0; i < 4; i++)
            Wt[(size_t)(bj + r + i * 8) * E_DIM + bi + c] = f2bf(tile[c][r + i * 8]);
    } else {
        // ---- concat + transpose + zero-pad query-proj weights ----
        const int idx = (bid - NLNB - NTRB) * 256 + threadIdx.x;  // 128*768
        const int rrow = idx / E_DIM, k = idx % E_DIM;
        float v = 0.f;
        if (rrow < 64) v = W_off[(size_t)k * 64 + rrow];
        else if (rrow < 96) v = W_attn[(size_t)k * 32 + (rrow - 64)];
        Wqc[idx] = f2bf(v);
        if (idx < 128) {
            float b = 0.f;
            if (idx < 64) b = b_off[idx];
            else if (idx < 96) b = b_attn[idx - 64];
            bcat[idx] = b;
        }
    }
}

// ---------------------------------------------------------------------------
// 128x128 NT-GEMM (round-1 verified structure), EPI=2 final residual only.
// ---------------------------------------------------------------------------
__global__ __launch_bounds__(256, 3) void mfma_gemm128(
    const unsigned short* __restrict__ A, const unsigned short* __restrict__ Bt,
    const float* __restrict__ bias, float* __restrict__ C, int ldC,
    const float* __restrict__ query, const float* __restrict__ qstats,
    const float* __restrict__ lnw, const float* __restrict__ lnb,
    const float* __restrict__ gamma) {
    __shared__ unsigned short As[128 * 64];   // [kseg 0..7][row 0..127][8]
    __shared__ unsigned short Bs[128 * 64];

    constexpr int K = E_DIM;
    const int tid = threadIdx.x;
    const int wave = tid >> 6;
    const int lane = tid & 63;
    const int quad = lane >> 4;
    const int l16 = lane & 15;

    const int nwg = gridDim.x * gridDim.y;
    const int flat = blockIdx.y * gridDim.x + blockIdx.x;
    const int cpx = nwg >> 3;
    const int swz = (flat & 7) * cpx + (flat >> 3);
    const int bx = swz % gridDim.x;
    const int by = swz / gridDim.x;
    const int bm = by * 128;
    const int bn = bx * 128;
    const int wrow = wave >> 1, wcol = wave & 1;

    const unsigned short* arow[4];
    const unsigned short* brow[4];
    unsigned short* aldst[4];
    unsigned short* bldst[4];
    #pragma unroll
    for (int i = 0; i < 4; i++) {
        const int chunk = wave * 4 + i;
        const int s = chunk >> 1, r = (chunk & 1) * 64 + lane;
        arow[i] = A + (size_t)(bm + r) * K + s * 8;
        brow[i] = Bt + (size_t)(bn + r) * K + s * 8;
        aldst[i] = As + chunk * 512;
        bldst[i] = Bs + chunk * 512;
    }

    f4v acc[4][4] = {};

    for (int k0 = 0; k0 < K; k0 += 64) {
        #pragma unroll
        for (int i = 0; i < 4; i++)
            GLD16(arow[i] + k0, aldst[i]);
        #pragma unroll
        for (int i = 0; i < 4; i++)
            GLD16(brow[i] + k0, bldst[i]);

        __syncthreads();

        #pragma unroll
        for (int c = 0; c < 2; c++) {
            s8v af[4], bf[4];
            #pragma unroll
            for (int ti = 0; ti < 4; ti++)
                af[ti] = *(const s8v*)(As + ((size_t)((c * 4 + quad) * 128 + wrow * 64 + ti * 16 + l16)) * 8);
            #pragma unroll
            for (int tj = 0; tj < 4; tj++)
                bf[tj] = *(const s8v*)(Bs + ((size_t)((c * 4 + quad) * 128 + wcol * 64 + tj * 16 + l16)) * 8);
            #pragma unroll
            for (int ti = 0; ti < 4; ti++)
                #pragma unroll
                for (int tj = 0; tj < 4; tj++)
                    acc[ti][tj] = __builtin_amdgcn_mfma_f32_16x16x32_bf16(af[ti], bf[tj], acc[ti][tj], 0, 0, 0);
        }
        __syncthreads();
    }

    #pragma unroll
    for (int ti = 0; ti < 4; ti++) {
        const int gm_base = bm + wrow * 64 + ti * 16 + quad * 4;
        #pragma unroll
        for (int tj = 0; tj < 4; tj++) {
            const int gn = bn + wcol * 64 + tj * 16 + l16;
            const float bv = bias[gn];
            #pragma unroll
            for (int r = 0; r < 4; r++) {
                const int gm = gm_base + r;
                const float v = acc[ti][tj][r] + bv;
                const size_t idx = (size_t)gm * ldC + gn;
                const float qv = query[idx];
                const float qln = (qv - qstats[gm * 2]) * qstats[gm * 2 + 1] * lnw[gn] + lnb[gn];
                C[idx] = qv + gamma[gn] * (qln + v);
            }
        }
    }
}

// ---------------------------------------------------------------------------
// Fat main GEMM: blocks 0..431 = value 256x256 (r5/r9 measured-best schedule,
// verbatim); blocks 432..559 = offsets 128x128 GEMM (8-wave, single-buffered,
// __syncthreads — separate blocks, so no barrier coupling with value path).
// The 128 offsets blocks fill the idle CUs of the value path's round-2 tail
// (432 blocks at 1 block/CU = 1.69 rounds), replacing a standalone ~45 us
// serial-K-chain dispatch with ~free tail occupancy.
// ---------------------------------------------------------------------------
template <int G>
__device__ __forceinline__ void tigroup(const unsigned short* as_, const s8v (&bfr)[2][4],
                                        f4v (&acc)[8][4], int quad, int l16, int wrow) {
    s8v af[2][2];
    #pragma unroll
    for (int c = 0; c < 2; c++)
        #pragma unroll
        for (int m = 0; m < 2; m++)
            af[c][m] = *(const s8v*)(as_ + ((size_t)((c * 4 + quad) * 256 + wrow * 128 + (G * 2 + m) * 16 + l16)) * 8);
    #pragma unroll
    for (int c = 0; c < 2; c++)
        #pragma unroll
        for (int m = 0; m < 2; m++)
            #pragma unroll
            for (int n = 0; n < 4; n++)
                acc[G * 2 + m][n] = __builtin_amdgcn_mfma_f32_16x16x32_bf16(
                    af[c][m], bfr[c][n], acc[G * 2 + m][n], 0, 0, 0);
}

__global__ __launch_bounds__(512, 2) void mfma_gemm256(
    const unsigned short* __restrict__ A, const unsigned short* __restrict__ Bt,
    const float* __restrict__ bias, unsigned short* __restrict__ C,
    const unsigned short* __restrict__ Aq, const unsigned short* __restrict__ Wqc,
    const float* __restrict__ bcat, float* __restrict__ offattn) {
    __shared__ unsigned short As[2][256 * 64];
    __shared__ unsigned short Bs[2][256 * 64];

    constexpr int K = E_DIM;
    constexpr int NT = K / 64;                 // 12 K-tiles
    const int tid = threadIdx.x;
    const int wave = tid >> 6;                 // 0..7
    const int lane = tid & 63;
    const int quad = lane >> 4;
    const int l16 = lane & 15;

    if (blockIdx.x < NVALB) {
        // =================== value path (r5/r9 schedule, verbatim) ==========
        const int flat = blockIdx.x;
        const int cpx = NVALB >> 3;
        const int swz = (flat & 7) * cpx + (flat >> 3);
        const int bx = swz % 3;
        const int by = swz / 3;
        const int bm = by * 256;
        const int bn = bx * 256;
        const int wrow = wave >> 2;                // 0..1
        const int wcol = wave & 3;                 // 0..3

        const unsigned short* gsrc[4][2];
        int ldst[4][2];
        #pragma unroll
        for (int h = 0; h < 4; h++) {
            #pragma unroll
            for (int i = 0; i < 2; i++) {
                const int ch = wave * 2 + i;
                const int s = ch >> 1, rsub = ch & 1;
                const int rw = (h & 1) * 128 + rsub * 64 + lane;   // [0,256)
                const unsigned short* base = (h < 2) ? (A + (size_t)(bm + rw) * K)
                                                     : (Bt + (size_t)(bn + rw) * K);
                gsrc[h][i] = base + s * 8;
                ldst[h][i] = (s * 256 + rw) * 8;
            }
        }

        #define STAGE256(h, kt, buf) do { \
            unsigned short* lb_ = ((h) < 2 ? &As[(buf)][0] : &Bs[(buf)][0]); \
            GLD16(gsrc[h][0] + (size_t)(kt) * 64, lb_ + ldst[h][0]); \
            GLD16(gsrc[h][1] + (size_t)(kt) * 64, lb_ + ldst[h][1]); \
        } while (0)

        f4v acc[8][4] = {};

        #pragma unroll
        for (int h = 0; h < 4; h++) STAGE256(h, 0, 0);

        int cur = 0;
        for (int t = 0; t < NT; ++t) {
            const unsigned short* as_ = &As[cur][0];
            const unsigned short* bs_ = &Bs[cur][0];
            const int nb = cur ^ 1;
            const bool pf = (t + 1 < NT);

            if (pf) {
                STAGE256(0, t + 1, nb);
                asm volatile("s_waitcnt vmcnt(2)" ::: "memory");
            } else {
                asm volatile("s_waitcnt vmcnt(0)" ::: "memory");
            }
            __builtin_amdgcn_s_barrier();
            __builtin_amdgcn_sched_barrier(0);

            s8v bfr[2][4];
            #pragma unroll
            for (int c = 0; c < 2; c++)
                #pragma unroll
                for (int n = 0; n < 4; n++)
                    bfr[c][n] = *(const s8v*)(bs_ + ((size_t)((c * 4 + quad) * 256 + wcol * 64 + n * 16 + l16)) * 8);

            __builtin_amdgcn_s_setprio(1);
            tigroup<0>(as_, bfr, acc, quad, l16, wrow);
            __builtin_amdgcn_s_setprio(0);

            if (pf) STAGE256(1, t + 1, nb);
            __builtin_amdgcn_s_setprio(1);
            tigroup<1>(as_, bfr, acc, quad, l16, wrow);
            __builtin_amdgcn_s_setprio(0);

            if (pf) STAGE256(2, t + 1, nb);
            __builtin_amdgcn_s_setprio(1);
            tigroup<2>(as_, bfr, acc, quad, l16, wrow);
            __builtin_amdgcn_s_setprio(0);

            if (pf) STAGE256(3, t + 1, nb);
            s8v af3[2][2];
            #pragma unroll
            for (int c = 0; c < 2; c++)
                #pragma unroll
                for (int m = 0; m < 2; m++)
                    af3[c][m] = *(const s8v*)(as_ + ((size_t)((c * 4 + quad) * 256 + wrow * 128 + (6 + m) * 16 + l16)) * 8);
            asm volatile("s_waitcnt lgkmcnt(0)" ::: "memory");
            __builtin_amdgcn_sched_barrier(0);
            __builtin_amdgcn_s_barrier();
            __builtin_amdgcn_sched_barrier(0);
            __builtin_amdgcn_s_setprio(1);
            #pragma unroll
            for (int c = 0; c < 2; c++)
                #pragma unroll
                for (int m = 0; m < 2; m++)
                    #pragma unroll
                    for (int n = 0; n < 4; n++)
                        acc[6 + m][n] = __builtin_amdgcn_mfma_f32_16x16x32_bf16(
                            af3[c][m], bfr[c][n], acc[6 + m][n], 0, 0, 0);
            __builtin_amdgcn_s_setprio(0);

            cur ^= 1;
        }
        #undef STAGE256

        #pragma unroll
        for (int ti = 0; ti < 8; ti++) {
            const int gm_base = bm + wrow * 128 + ti * 16 + quad * 4;
            #pragma unroll
            for (int tj = 0; tj < 4; tj++) {
                const int gn = bn + wcol * 64 + tj * 16 + l16;
                const float bv = bias[gn];
                const int hh = gn / HDIM, dd = gn - hh * HDIM;
                #pragma unroll
                for (int r = 0; r < 4; r++) {
                    const int gm = gm_base + r;
                    const float v = acc[ti][tj][r] + bv;
                    const int b = gm / NVS, s = gm - b * NVS;
                    const size_t vidx = (((size_t)b * NHEAD + hh) * NVS + s) * HDIM + dd;
                    C[vidx] = f2bf(v);
                }
            }
        }
    } else {
        // ============== offsets path: 128x128, 8 waves, single-buffered =====
        const int bm = (blockIdx.x - NVALB) * 128;
        const int wrow = wave >> 2;                // 0..1 (64-row halves)
        const int wcol = wave & 3;                 // 0..3 (32-col quarters)
        unsigned short* As0 = &As[0][0];           // reuse 16 KB of value LDS
        unsigned short* Bs0 = &Bs[0][0];

        const unsigned short* arow[2];
        const unsigned short* brow[2];
        int loff[2];
        #pragma unroll
        for (int i = 0; i < 2; i++) {
            const int ch = wave * 2 + i;           // 0..15
            const int s = ch >> 1, r = (ch & 1) * 64 + lane;   // kseg, row
            arow[i] = Aq + (size_t)(bm + r) * K + s * 8;
            brow[i] = Wqc + (size_t)r * K + s * 8;             // 128 rows total
            loff[i] = (s * 128 + r) * 8;
        }

        f4v accq[4][2] = {};

        for (int k0 = 0; k0 < K; k0 += 64) {
            #pragma unroll
            for (int i = 0; i < 2; i++) GLD16(arow[i] + k0, As0 + loff[i]);
            #pragma unroll
            for (int i = 0; i < 2; i++) GLD16(brow[i] + k0, Bs0 + loff[i]);

            __syncthreads();

            #pragma unroll
            for (int c = 0; c < 2; c++) {
                s8v af[4], bf[2];
                #pragma unroll
                for (int m = 0; m < 4; m++)
                    af[m] = *(const s8v*)(As0 + ((size_t)((c * 4 + quad) * 128 + wrow * 64 + m * 16 + l16)) * 8);
                #pragma unroll
                for (int n = 0; n < 2; n++)
                    bf[n] = *(const s8v*)(Bs0 + ((size_t)((c * 4 + quad) * 128 + wcol * 32 + n * 16 + l16)) * 8);
                #pragma unroll
                for (int m = 0; m < 4; m++)
                    #pragma unroll
                    for (int n = 0; n < 2; n++)
                        accq[m][n] = __builtin_amdgcn_mfma_f32_16x16x32_bf16(af[m], bf[n], accq[m][n], 0, 0, 0);
            }
            __syncthreads();
        }

        #pragma unroll
        for (int m = 0; m < 4; m++) {
            const int gm_base = bm + wrow * 64 + m * 16 + quad * 4;
            #pragma unroll
            for (int n = 0; n < 2; n++) {
                const int gn = wcol * 32 + n * 16 + l16;
                const float bv = bcat[gn];
                #pragma unroll
                for (int r = 0; r < 4; r++)
                    offattn[(size_t)(gm_base + r) * 128 + gn] = accq[m][n][r] + bv;
            }
        }
    }
}

// ---------------------------------------------------------------------------
// MSDA core: grid (8 heads, 512); block 384 = 32 rows x 12 lanes.
// Preamble spread over 128 threads (4-lane shuffle softmax).
// ---------------------------------------------------------------------------
__global__ __launch_bounds__(384) void msda_kernel(
    const unsigned short* __restrict__ value,  // (B, 8, 9216, 96) bf16
    const float* __restrict__ oa,              // (B*NQ, 128): 0-63 off, 64-95 attn
    const float* __restrict__ refp,            // (B*NQ, 2)
    unsigned short* __restrict__ out) {        // (B*NQ, 768) bf16
    const int h = blockIdx.x;
    const int row0 = blockIdx.y * 32;
    const int t = threadIdx.x;

    __shared__ float x_s[128], y_s[128], aw_s[128];
    if (t < 128) {
        const int r = t >> 2, p = t & 3;       // 4-lane group per row (aligned)
        const int row = row0 + r;
        const float* oar = oa + (size_t)row * 128;
        float a = oar[64 + h * 4 + p];
        float mx = fmaxf(a, __shfl_xor(a, 1, 64));
        mx = fmaxf(mx, __shfl_xor(mx, 2, 64));
        float e = __expf(a - mx);
        float sden = e + __shfl_xor(e, 1, 64);
        sden += __shfl_xor(sden, 2, 64);
        aw_s[t] = e / sden;
        const float rx = refp[(size_t)row * 2 + 0] * WFEAT - 0.5f;
        const float ry = refp[(size_t)row * 2 + 1] * HFEAT - 0.5f;
        x_s[t] = rx + oar[h * 8 + p * 2 + 0];
        y_s[t] = ry + oar[h * 8 + p * 2 + 1];
    }
    __syncthreads();

    const int r = t / 12;              // 0..31
    const int j = t - r * 12;          // 0..11
    const int row = row0 + r;
    const int b = row >> 12;           // / NQS
    const unsigned short* vb = value + ((size_t)(b * NHEAD + h) * NVS) * HDIM + j * 8;

    float acc[8] = {};
    #pragma unroll
    for (int p = 0; p < 4; p++) {
        const float x = x_s[r * 4 + p];
        const float y = y_s[r * 4 + p];
        const float aw = aw_s[r * 4 + p];
        const float x0f = floorf(x), y0f = floorf(y);
        const float fx = x - x0f, fy = y - y0f;
        const int ix0 = (int)x0f, iy0 = (int)y0f;
        const int ix1 = ix0 + 1, iy1 = iy0 + 1;
        const float wx0 = (ix0 >= 0 && ix0 < WFEAT) ? (1.f - fx) : 0.f;
        const float wx1 = (ix1 >= 0 && ix1 < WFEAT) ? fx : 0.f;
        const float wy0 = (iy0 >= 0 && iy0 < HFEAT) ? (1.f - fy) : 0.f;
        const float wy1 = (iy1 >= 0 && iy1 < HFEAT) ? fy : 0.f;
        const int cx0 = min(max(ix0, 0), WFEAT - 1);
        const int cx1 = min(max(ix1, 0), WFEAT - 1);
        const int cy0 = min(max(iy0, 0), HFEAT - 1);
        const int cy1 = min(max(iy1, 0), HFEAT - 1);
        const float w00 = aw * wy0 * wx0, w01 = aw * wy0 * wx1;
        const float w10 = aw * wy1 * wx0, w11 = aw * wy1 * wx1;
        const s8v v00 = *(const s8v*)(vb + (size_t)(cy0 * WFEAT + cx0) * HDIM);
        const s8v v01 = *(const s8v*)(vb + (size_t)(cy0 * WFEAT + cx1) * HDIM);
        const s8v v10 = *(const s8v*)(vb + (size_t)(cy1 * WFEAT + cx0) * HDIM);
        const s8v v11 = *(const s8v*)(vb + (size_t)(cy1 * WFEAT + cx1) * HDIM);
        #pragma unroll
        for (int k = 0; k < 8; k++) {
            acc[k] += w00 * bf2f_s(v00[k]) + w01 * bf2f_s(v01[k])
                    + w10 * bf2f_s(v10[k]) + w11 * bf2f_s(v11[k]);
        }
    }

    s8v o;
    #pragma unroll
    for (int k = 0; k < 8; k++) o[k] = (short)f2bf(acc[k]);
    *(s8v*)(out + (size_t)row * E_DIM + h * HDIM + j * 8) = o;
}

// ---------------------------------------------------------------------------
extern "C" void kernel_launch(void* const* d_in, const int* in_sizes, int n_in,
                              void* d_out, int out_size, void* d_ws, size_t ws_size,
                              hipStream_t stream) {
    (void)in_sizes; (void)n_in; (void)out_size; (void)ws_size;

    const float* query  = (const float*)d_in[0];
    const float* refp   = (const float*)d_in[1];
    const float* feat   = (const float*)d_in[2];
    const float* ln_q_w = (const float*)d_in[5];
    const float* ln_q_b = (const float*)d_in[6];
    const float* ln_f_w = (const float*)d_in[7];
    const float* ln_f_b = (const float*)d_in[8];
    const float* W_val  = (const float*)d_in[9];
    const float* b_val  = (const float*)d_in[10];
    const float* W_off  = (const float*)d_in[11];
    const float* b_off  = (const float*)d_in[12];
    const float* W_attn = (const float*)d_in[13];
    const float* b_attn = (const float*)d_in[14];
    const float* W_out  = (const float*)d_in[15];
    const float* b_out  = (const float*)d_in[16];
    const float* gamma  = (const float*)d_in[17];
    float* out = (float*)d_out;

    const int MQ = BB * NQS;   // 16384
    const int MV = BB * NVS;   // 36864

    // Workspace layout (bytes)
    char* ws = (char*)d_ws;
    float*          q_stats = (float*)(ws + 0);                   //     131,072
    unsigned short* qbf     = (unsigned short*)(ws + 131072);     //  25,165,824
    unsigned short* fbf     = (unsigned short*)(ws + 25296896);   //  56,623,104
    unsigned short* val_bf  = (unsigned short*)(ws + 81920000);   //  56,623,104 (B,H,S,D)
    unsigned short* msda_bf = (unsigned short*)(ws + 138543104);  //  25,165,824
    float*          offattn = (float*)(ws + 163708928);           //   8,388,608
    unsigned short* Wv_t    = (unsigned short*)(ws + 172097536);  //   1,179,648
    unsigned short* Wo_t    = (unsigned short*)(ws + 173277184);  //   1,179,648
    unsigned short* Wqc_t   = (unsigned short*)(ws + 174456832);  //     196,608
    float*          bcat    = (float*)(ws + 174653440);           //         512

    // 1. prep: LN (query+feat) + both weight transposes + wqc concat
    prep_kernel<<<NLNB + NTRB + 384, 256, 0, stream>>>(
        query, feat, ln_q_w, ln_q_b, ln_f_w, ln_f_b, qbf, fbf, q_stats,
        W_val, W_out, Wv_t, Wo_t, W_off, W_attn, b_off, b_attn, Wqc_t, bcat);

    // 2. fat GEMM: value (256^2, 432 blocks) + offsets (128^2, 128 blocks in tail)
    mfma_gemm256<<<NVALB + 128, 512, 0, stream>>>(
        fbf, Wv_t, b_val, val_bf, qbf, Wqc_t, bcat, offattn);

    // 3. deformable sampling -> bf16 (row-major B*NQ x 768)
    msda_kernel<<<dim3(NHEAD, MQ / 32), 384, 0, stream>>>(val_bf, offattn, refp, msda_bf);

    // 4. out-proj + fused final residual (128^2: 768 blocks = 3/CU)
    mfma_gemm128<<<dim3(E_DIM / 128, MQ / 128), 256, 0, stream>>>(
        msda_bf, Wo_t, b_out, out, E_DIM, query, q_stats, ln_q_w, ln_q_b, gamma);
}

// Round 13
// 419.021 us; speedup vs baseline: 1.1221x; 1.0571x over previous
//
#include <hip/hip_runtime.h>

#define BB     4
#define NQS    4096
#define NVS    9216
#define E_DIM  768
#define NHEAD  8
#define NPTS   4
#define HDIM   96
#define HFEAT  96
#define WFEAT  96
#define MQR    16384   // BB*NQS
#define NLNB   13312   // (MQ+MV)/4 ln blocks
#define NTRB   1152    // 24*24*2 transpose blocks
#define NVALB  432     // value-gemm blocks (3 x 144)
#define OROWS  64      // rows per fused msda+outproj block

typedef __attribute__((ext_vector_type(8))) short  s8v;    // 8 x bf16 (4 VGPRs)
typedef __attribute__((ext_vector_type(4))) short  s4v;    // 4 x bf16
typedef __attribute__((ext_vector_type(4))) float  f4v;    // MFMA acc

__device__ __forceinline__ unsigned short f2bf(float x) {
    unsigned int u = __builtin_bit_cast(unsigned int, x);
    unsigned int r = (u + 0x7fffu + ((u >> 16) & 1u)) >> 16;
    return (unsigned short)r;
}
__device__ __forceinline__ float bf2f(unsigned short s) {
    unsigned int u = ((unsigned int)s) << 16;
    return __builtin_bit_cast(float, u);
}
__device__ __forceinline__ float bf2f_s(short s) {
    return bf2f((unsigned short)s);
}

#define GLD16(gp, lp) \
    __builtin_amdgcn_global_load_lds( \
        (__attribute__((address_space(1))) void*)(gp), \
        (__attribute__((address_space(3))) void*)(lp), 16, 0, 0)

// ---------------------------------------------------------------------------
// Fat prep kernel: ln_fused (blocks 0..13311) | weight transpose (next 1152)
// | wqc concat (last 384). 256 threads each; one launch instead of three.
// ---------------------------------------------------------------------------
__global__ __launch_bounds__(256) void prep_kernel(
    const float* __restrict__ q, const float* __restrict__ f,
    const float* __restrict__ qw, const float* __restrict__ qb,
    const float* __restrict__ fw, const float* __restrict__ fb,
    unsigned short* __restrict__ qout, unsigned short* __restrict__ fout,
    float* __restrict__ stats,
    const float* __restrict__ W0, const float* __restrict__ W1,
    unsigned short* __restrict__ T0, unsigned short* __restrict__ T1,
    const float* __restrict__ W_off, const float* __restrict__ W_attn,
    const float* __restrict__ b_off, const float* __restrict__ b_attn,
    unsigned short* __restrict__ Wqc, float* __restrict__ bcat) {
    __shared__ float tile[32][33];
    const int bid = blockIdx.x;

    if (bid < NLNB) {
        // ---- LayerNorm + bf16 cast: one wave per row, shuffle reduce ----
        const int wv = threadIdx.x >> 6, lane = threadIdx.x & 63;
        const int row = bid * 4 + wv;
        const bool isq = row < MQR;
        const float* x = isq ? (q + (size_t)row * E_DIM)
                             : (f + (size_t)(row - MQR) * E_DIM);
        const float4 v0 = ((const float4*)x)[lane];
        const float4 v1 = ((const float4*)x)[lane + 64];
        const float4 v2 = ((const float4*)x)[lane + 128];
        float s1 = v0.x + v0.y + v0.z + v0.w + v1.x + v1.y + v1.z + v1.w
                 + v2.x + v2.y + v2.z + v2.w;
        float s2 = v0.x * v0.x + v0.y * v0.y + v0.z * v0.z + v0.w * v0.w
                 + v1.x * v1.x + v1.y * v1.y + v1.z * v1.z + v1.w * v1.w
                 + v2.x * v2.x + v2.y * v2.y + v2.z * v2.z + v2.w * v2.w;
        #pragma unroll
        for (int o = 32; o > 0; o >>= 1) {
            s1 += __shfl_down(s1, o, 64);
            s2 += __shfl_down(s2, o, 64);
        }
        const float mean = __shfl(s1, 0, 64) * (1.0f / E_DIM);
        const float m2   = __shfl(s2, 0, 64) * (1.0f / E_DIM);
        const float rstd = rsqrtf(m2 - mean * mean + 1e-6f);
        if (isq && lane == 0) { stats[row * 2] = mean; stats[row * 2 + 1] = rstd; }
        const float* w = isq ? qw : fw;
        const float* b = isq ? qb : fb;
        unsigned short* o = isq ? (qout + (size_t)row * E_DIM)
                                : (fout + (size_t)(row - MQR) * E_DIM);
        const float4 vv[3] = {v0, v1, v2};
        #pragma unroll
        for (int c = 0; c < 3; c++) {
            const float4 w4 = ((const float4*)w)[lane + c * 64];
            const float4 b4 = ((const float4*)b)[lane + c * 64];
            s4v ov;
            ov[0] = (short)f2bf((vv[c].x - mean) * rstd * w4.x + b4.x);
            ov[1] = (short)f2bf((vv[c].y - mean) * rstd * w4.y + b4.y);
            ov[2] = (short)f2bf((vv[c].z - mean) * rstd * w4.z + b4.z);
            ov[3] = (short)f2bf((vv[c].w - mean) * rstd * w4.w + b4.w);
            ((s4v*)o)[lane + c * 64] = ov;
        }
    } else if (bid < NLNB + NTRB) {
        // ---- 32x32 transpose + bf16 cast of W_val / W_out ----
        const int idx = bid - NLNB;
        const int z = idx / 576, r2 = idx - z * 576;
        const float* W = z ? W1 : W0;
        unsigned short* Wt = z ? T1 : T0;
        const int bi = (r2 / 24) * 32, bj = (r2 % 24) * 32;
        const int t = threadIdx.x;
        const int r = t >> 5, c = t & 31;
        #pragma unroll
        for (int i = 0; i < 4; i++)
            tile[r + i * 8][c] = W[(size_t)(bi + r + i * 8) * E_DIM + bj + c];
        __syncthreads();
        #pragma unroll
        for (int i = 0; i < 4; i++)
            Wt[(size_t)(bj + r + i * 8) * E_DIM + bi + c] = f2bf(tile[c][r + i * 8]);
    } else {
        // ---- concat + transpose + zero-pad query-proj weights ----
        const int idx = (bid - NLNB - NTRB) * 256 + threadIdx.x;  // 128*768
        const int rrow = idx / E_DIM, k = idx % E_DIM;
        float v = 0.f;
        if (rrow < 64) v = W_off[(size_t)k * 64 + rrow];
        else if (rrow < 96) v = W_attn[(size_t)k * 32 + (rrow - 64)];
        Wqc[idx] = f2bf(v);
        if (idx < 128) {
            float b = 0.f;
            if (idx < 64) b = b_off[idx];
            else if (idx < 96) b = b_attn[idx - 64];
            bcat[idx] = b;
        }
    }
}

// ---------------------------------------------------------------------------
// Fat main GEMM (r12, unchanged): blocks 0..431 = value 256x256 (r5/r9
// schedule); blocks 432..559 = offsets 128x128 GEMM in the tail.
// ---------------------------------------------------------------------------
template <int G>
__device__ __forceinline__ void tigroup(const unsigned short* as_, const s8v (&bfr)[2][4],
                                        f4v (&acc)[8][4], int quad, int l16, int wrow) {
    s8v af[2][2];
    #pragma unroll
    for (int c = 0; c < 2; c++)
        #pragma unroll
        for (int m = 0; m < 2; m++)
            af[c][m] = *(const s8v*)(as_ + ((size_t)((c * 4 + quad) * 256 + wrow * 128 + (G * 2 + m) * 16 + l16)) * 8);
    #pragma unroll
    for (int c = 0; c < 2; c++)
        #pragma unroll
        for (int m = 0; m < 2; m++)
            #pragma unroll
            for (int n = 0; n < 4; n++)
                acc[G * 2 + m][n] = __builtin_amdgcn_mfma_f32_16x16x32_bf16(
                    af[c][m], bfr[c][n], acc[G * 2 + m][n], 0, 0, 0);
}

__global__ __launch_bounds__(512, 2) void mfma_gemm256(
    const unsigned short* __restrict__ A, const unsigned short* __restrict__ Bt,
    const float* __restrict__ bias, unsigned short* __restrict__ C,
    const unsigned short* __restrict__ Aq, const unsigned short* __restrict__ Wqc,
    const float* __restrict__ bcat, float* __restrict__ offattn) {
    __shared__ unsigned short As[2][256 * 64];
    __shared__ unsigned short Bs[2][256 * 64];

    constexpr int K = E_DIM;
    constexpr int NT = K / 64;                 // 12 K-tiles
    const int tid = threadIdx.x;
    const int wave = tid >> 6;                 // 0..7
    const int lane = tid & 63;
    const int quad = lane >> 4;
    const int l16 = lane & 15;

    if (blockIdx.x < NVALB) {
        // =================== value path (r5/r9 schedule, verbatim) ==========
        const int flat = blockIdx.x;
        const int cpx = NVALB >> 3;
        const int swz = (flat & 7) * cpx + (flat >> 3);
        const int bx = swz % 3;
        const int by = swz / 3;
        const int bm = by * 256;
        const int bn = bx * 256;
        const int wrow = wave >> 2;                // 0..1
        const int wcol = wave & 3;                 // 0..3

        const unsigned short* gsrc[4][2];
        int ldst[4][2];
        #pragma unroll
        for (int h = 0; h < 4; h++) {
            #pragma unroll
            for (int i = 0; i < 2; i++) {
                const int ch = wave * 2 + i;
                const int s = ch >> 1, rsub = ch & 1;
                const int rw = (h & 1) * 128 + rsub * 64 + lane;   // [0,256)
                const unsigned short* base = (h < 2) ? (A + (size_t)(bm + rw) * K)
                                                     : (Bt + (size_t)(bn + rw) * K);
                gsrc[h][i] = base + s * 8;
                ldst[h][i] = (s * 256 + rw) * 8;
            }
        }

        #define STAGE256(h, kt, buf) do { \
            unsigned short* lb_ = ((h) < 2 ? &As[(buf)][0] : &Bs[(buf)][0]); \
            GLD16(gsrc[h][0] + (size_t)(kt) * 64, lb_ + ldst[h][0]); \
            GLD16(gsrc[h][1] + (size_t)(kt) * 64, lb_ + ldst[h][1]); \
        } while (0)

        f4v acc[8][4] = {};

        #pragma unroll
        for (int h = 0; h < 4; h++) STAGE256(h, 0, 0);

        int cur = 0;
        for (int t = 0; t < NT; ++t) {
            const unsigned short* as_ = &As[cur][0];
            const unsigned short* bs_ = &Bs[cur][0];
            const int nb = cur ^ 1;
            const bool pf = (t + 1 < NT);

            if (pf) {
                STAGE256(0, t + 1, nb);
                asm volatile("s_waitcnt vmcnt(2)" ::: "memory");
            } else {
                asm volatile("s_waitcnt vmcnt(0)" ::: "memory");
            }
            __builtin_amdgcn_s_barrier();
            __builtin_amdgcn_sched_barrier(0);

            s8v bfr[2][4];
            #pragma unroll
            for (int c = 0; c < 2; c++)
                #pragma unroll
                for (int n = 0; n < 4; n++)
                    bfr[c][n] = *(const s8v*)(bs_ + ((size_t)((c * 4 + quad) * 256 + wcol * 64 + n * 16 + l16)) * 8);

            __builtin_amdgcn_s_setprio(1);
            tigroup<0>(as_, bfr, acc, quad, l16, wrow);
            __builtin_amdgcn_s_setprio(0);

            if (pf) STAGE256(1, t + 1, nb);
            __builtin_amdgcn_s_setprio(1);
            tigroup<1>(as_, bfr, acc, quad, l16, wrow);
            __builtin_amdgcn_s_setprio(0);

            if (pf) STAGE256(2, t + 1, nb);
            __builtin_amdgcn_s_setprio(1);
            tigroup<2>(as_, bfr, acc, quad, l16, wrow);
            __builtin_amdgcn_s_setprio(0);

            if (pf) STAGE256(3, t + 1, nb);
            s8v af3[2][2];
            #pragma unroll
            for (int c = 0; c < 2; c++)
                #pragma unroll
                for (int m = 0; m < 2; m++)
                    af3[c][m] = *(const s8v*)(as_ + ((size_t)((c * 4 + quad) * 256 + wrow * 128 + (6 + m) * 16 + l16)) * 8);
            asm volatile("s_waitcnt lgkmcnt(0)" ::: "memory");
            __builtin_amdgcn_sched_barrier(0);
            __builtin_amdgcn_s_barrier();
            __builtin_amdgcn_sched_barrier(0);
            __builtin_amdgcn_s_setprio(1);
            #pragma unroll
            for (int c = 0; c < 2; c++)
                #pragma unroll
                for (int m = 0; m < 2; m++)
                    #pragma unroll
                    for (int n = 0; n < 4; n++)
                        acc[6 + m][n] = __builtin_amdgcn_mfma_f32_16x16x32_bf16(
                            af3[c][m], bfr[c][n], acc[6 + m][n], 0, 0, 0);
            __builtin_amdgcn_s_setprio(0);

            cur ^= 1;
        }
        #undef STAGE256

        #pragma unroll
        for (int ti = 0; ti < 8; ti++) {
            const int gm_base = bm + wrow * 128 + ti * 16 + quad * 4;
            #pragma unroll
            for (int tj = 0; tj < 4; tj++) {
                const int gn = bn + wcol * 64 + tj * 16 + l16;
                const float bv = bias[gn];
                const int hh = gn / HDIM, dd = gn - hh * HDIM;
                #pragma unroll
                for (int r = 0; r < 4; r++) {
                    const int gm = gm_base + r;
                    const float v = acc[ti][tj][r] + bv;
                    const int b = gm / NVS, s = gm - b * NVS;
                    const size_t vidx = (((size_t)b * NHEAD + hh) * NVS + s) * HDIM + dd;
                    C[vidx] = f2bf(v);
                }
            }
        }
    } else {
        // ============== offsets path: 128x128, 8 waves, single-buffered =====
        const int bm = (blockIdx.x - NVALB) * 128;
        const int wrow = wave >> 2;                // 0..1 (64-row halves)
        const int wcol = wave & 3;                 // 0..3 (32-col quarters)
        unsigned short* As0 = &As[0][0];           // reuse 16 KB of value LDS
        unsigned short* Bs0 = &Bs[0][0];

        const unsigned short* arow[2];
        const unsigned short* brow[2];
        int loff[2];
        #pragma unroll
        for (int i = 0; i < 2; i++) {
            const int ch = wave * 2 + i;           // 0..15
            const int s = ch >> 1, r = (ch & 1) * 64 + lane;   // kseg, row
            arow[i] = Aq + (size_t)(bm + r) * K + s * 8;
            brow[i] = Wqc + (size_t)r * K + s * 8;             // 128 rows total
            loff[i] = (s * 128 + r) * 8;
        }

        f4v accq[4][2] = {};

        for (int k0 = 0; k0 < K; k0 += 64) {
            #pragma unroll
            for (int i = 0; i < 2; i++) GLD16(arow[i] + k0, As0 + loff[i]);
            #pragma unroll
            for (int i = 0; i < 2; i++) GLD16(brow[i] + k0, Bs0 + loff[i]);

            __syncthreads();

            #pragma unroll
            for (int c = 0; c < 2; c++) {
                s8v af[4], bf[2];
                #pragma unroll
                for (int m = 0; m < 4; m++)
                    af[m] = *(const s8v*)(As0 + ((size_t)((c * 4 + quad) * 128 + wrow * 64 + m * 16 + l16)) * 8);
                #pragma unroll
                for (int n = 0; n < 2; n++)
                    bf[n] = *(const s8v*)(Bs0 + ((size_t)((c * 4 + quad) * 128 + wcol * 32 + n * 16 + l16)) * 8);
                #pragma unroll
                for (int m = 0; m < 4; m++)
                    #pragma unroll
                    for (int n = 0; n < 2; n++)
                        accq[m][n] = __builtin_amdgcn_mfma_f32_16x16x32_bf16(af[m], bf[n], accq[m][n], 0, 0, 0);
            }
            __syncthreads();
        }

        #pragma unroll
        for (int m = 0; m < 4; m++) {
            const int gm_base = bm + wrow * 64 + m * 16 + quad * 4;
            #pragma unroll
            for (int n = 0; n < 2; n++) {
                const int gn = wcol * 32 + n * 16 + l16;
                const float bv = bcat[gn];
                #pragma unroll
                for (int r = 0; r < 4; r++)
                    offattn[(size_t)(gm_base + r) * 128 + gn] = accq[m][n][r] + bv;
            }
        }
    }
}

// ---------------------------------------------------------------------------
// Fused MSDA + out-proj + final residual. Grid 256 blocks x 512 thr (8 waves),
// 1 block/CU (96 KB LDS). Each block owns 64 query rows (single batch:
// 4096/64 = 64 blocks per batch).
// Phase 1: 6144 (row,head,j) msda tasks, 12/thread; result bf16 into LDS
//   Ams[64][768] with 16B-granular XOR swizzle (col16 ^= r&7) — without it
//   the GEMM A-read (1536B row stride) is a 16-way bank conflict.
// Phase 2: 64x768 GEMM: A from swizzled LDS; B = Wo_t (1.18 MB, L2-resident,
//   round-0-proven direct-global fragments); 24 K-steps x 24 MFMA/wave;
//   fused EPI2 epilogue (qln from stats + residual).
// Eliminates: msda_bf HBM round-trip (50 MB), one kernel boundary, and
// out-proj's LDS staging.
// ---------------------------------------------------------------------------
__global__ __launch_bounds__(512, 2) void msda_oproj_kernel(
    const unsigned short* __restrict__ value,  // (B, 8, 9216, 96) bf16
    const float* __restrict__ oa,              // (MQR, 128): 0-63 off, 64-95 attn
    const float* __restrict__ refp,            // (MQR, 2)
    const unsigned short* __restrict__ Wo,     // Wo_t [n][k] 768x768 bf16
    const float* __restrict__ bias,            // b_out
    const float* __restrict__ query, const float* __restrict__ qstats,
    const float* __restrict__ lnw, const float* __restrict__ lnb,
    const float* __restrict__ gamma, float* __restrict__ out) {
    __shared__ unsigned short Ams[OROWS * E_DIM];   // 96 KB

    const int row0 = blockIdx.x * OROWS;
    const int t = threadIdx.x;
    const int b = row0 >> 12;                  // uniform per block

    // ---------------- phase 1: msda -> LDS ----------------
    #pragma unroll
    for (int it = 0; it < 12; ++it) {
        const int tt = it * 512 + t;           // 0..6143
        const int r = tt / 96;
        const int rem = tt - r * 96;
        const int h = rem / 12;
        const int j = rem - h * 12;
        const int row = row0 + r;
        const float* oar = oa + (size_t)row * 128;
        float a0 = oar[64 + h * 4 + 0], a1 = oar[64 + h * 4 + 1];
        float a2 = oar[64 + h * 4 + 2], a3 = oar[64 + h * 4 + 3];
        float mx = fmaxf(fmaxf(a0, a1), fmaxf(a2, a3));
        float e0 = __expf(a0 - mx), e1 = __expf(a1 - mx);
        float e2 = __expf(a2 - mx), e3 = __expf(a3 - mx);
        float inv = 1.0f / (e0 + e1 + e2 + e3);
        const float aww[4] = {e0 * inv, e1 * inv, e2 * inv, e3 * inv};
        const float rx = refp[(size_t)row * 2 + 0] * WFEAT - 0.5f;
        const float ry = refp[(size_t)row * 2 + 1] * HFEAT - 0.5f;
        const unsigned short* vb = value + ((size_t)(b * NHEAD + h) * NVS) * HDIM + j * 8;

        float acc[8] = {};
        #pragma unroll
        for (int p = 0; p < 4; p++) {
            const float x = rx + oar[h * 8 + p * 2 + 0];
            const float y = ry + oar[h * 8 + p * 2 + 1];
            const float aw = aww[p];
            const float x0f = floorf(x), y0f = floorf(y);
            const float fx = x - x0f, fy = y - y0f;
            const int ix0 = (int)x0f, iy0 = (int)y0f;
            const int ix1 = ix0 + 1, iy1 = iy0 + 1;
            const float wx0 = (ix0 >= 0 && ix0 < WFEAT) ? (1.f - fx) : 0.f;
            const float wx1 = (ix1 >= 0 && ix1 < WFEAT) ? fx : 0.f;
            const float wy0 = (iy0 >= 0 && iy0 < HFEAT) ? (1.f - fy) : 0.f;
            const float wy1 = (iy1 >= 0 && iy1 < HFEAT) ? fy : 0.f;
            const int cx0 = min(max(ix0, 0), WFEAT - 1);
            const int cx1 = min(max(ix1, 0), WFEAT - 1);
            const int cy0 = min(max(iy0, 0), HFEAT - 1);
            const int cy1 = min(max(iy1, 0), HFEAT - 1);
            const float w00 = aw * wy0 * wx0, w01 = aw * wy0 * wx1;
            const float w10 = aw * wy1 * wx0, w11 = aw * wy1 * wx1;
            const s8v v00 = *(const s8v*)(vb + (size_t)(cy0 * WFEAT + cx0) * HDIM);
            const s8v v01 = *(const s8v*)(vb + (size_t)(cy0 * WFEAT + cx1) * HDIM);
            const s8v v10 = *(const s8v*)(vb + (size_t)(cy1 * WFEAT + cx0) * HDIM);
            const s8v v11 = *(const s8v*)(vb + (size_t)(cy1 * WFEAT + cx1) * HDIM);
            #pragma unroll
            for (int k = 0; k < 8; k++) {
                acc[k] += w00 * bf2f_s(v00[k]) + w01 * bf2f_s(v01[k])
                        + w10 * bf2f_s(v10[k]) + w11 * bf2f_s(v11[k]);
            }
        }
        s8v o;
        #pragma unroll
        for (int k = 0; k < 8; k++) o[k] = (short)f2bf(acc[k]);
        const int col16 = (h * 12 + j) ^ (r & 7);          // swizzled 16B slot
        *(s8v*)(&Ams[((size_t)r * 96 + col16) * 8]) = o;
    }
    __syncthreads();

    // ---------------- phase 2: 64x768 GEMM + residual ----------------
    const int wave = t >> 6;                   // 0..7 -> col block wave*96
    const int lane = t & 63;
    const int quad = lane >> 4;
    const int l16 = lane & 15;

    const unsigned short* bcol[6];
    #pragma unroll
    for (int n = 0; n < 6; n++)
        bcol[n] = Wo + (size_t)(wave * 96 + n * 16 + l16) * E_DIM + quad * 8;

    f4v acc[4][6] = {};

    for (int k0 = 0; k0 < E_DIM; k0 += 32) {
        const int kc = (k0 >> 3) + quad;       // A col16 before swizzle
        s8v af[4], bf[6];
        #pragma unroll
        for (int m = 0; m < 4; m++) {
            const int r = m * 16 + l16;
            af[m] = *(const s8v*)(&Ams[((size_t)r * 96 + (kc ^ (r & 7))) * 8]);
        }
        #pragma unroll
        for (int n = 0; n < 6; n++)
            bf[n] = *(const s8v*)(bcol[n] + k0);
        #pragma unroll
        for (int m = 0; m < 4; m++)
            #pragma unroll
            for (int n = 0; n < 6; n++)
                acc[m][n] = __builtin_amdgcn_mfma_f32_16x16x32_bf16(af[m], bf[n], acc[m][n], 0, 0, 0);
    }

    #pragma unroll
    for (int m = 0; m < 4; m++) {
        const int gm_base = row0 + m * 16 + quad * 4;
        #pragma unroll
        for (int n = 0; n < 6; n++) {
            const int gn = wave * 96 + n * 16 + l16;
            const float bv = bias[gn];
            #pragma unroll
            for (int r = 0; r < 4; r++) {
                const int gm = gm_base + r;
                const size_t idx = (size_t)gm * E_DIM + gn;
                const float qv = query[idx];
                const float qln = (qv - qstats[gm * 2]) * qstats[gm * 2 + 1] * lnw[gn] + lnb[gn];
                out[idx] = qv + gamma[gn] * (qln + acc[m][n][r] + bv);
            }
        }
    }
}

// ---------------------------------------------------------------------------
extern "C" void kernel_launch(void* const* d_in, const int* in_sizes, int n_in,
                              void* d_out, int out_size, void* d_ws, size_t ws_size,
                              hipStream_t stream) {
    (void)in_sizes; (void)n_in; (void)out_size; (void)ws_size;

    const float* query  = (const float*)d_in[0];
    const float* refp   = (const float*)d_in[1];
    const float* feat   = (const float*)d_in[2];
    const float* ln_q_w = (const float*)d_in[5];
    const float* ln_q_b = (const float*)d_in[6];
    const float* ln_f_w = (const float*)d_in[7];
    const float* ln_f_b = (const float*)d_in[8];
    const float* W_val  = (const float*)d_in[9];
    const float* b_val  = (const float*)d_in[10];
    const float* W_off  = (const float*)d_in[11];
    const float* b_off  = (const float*)d_in[12];
    const float* W_attn = (const float*)d_in[13];
    const float* b_attn = (const float*)d_in[14];
    const float* W_out  = (const float*)d_in[15];
    const float* b_out  = (const float*)d_in[16];
    const float* gamma  = (const float*)d_in[17];
    float* out = (float*)d_out;

    const int MQ = BB * NQS;   // 16384
    const int MV = BB * NVS;   // 36864

    // Workspace layout (bytes)
    char* ws = (char*)d_ws;
    float*          q_stats = (float*)(ws + 0);                   //     131,072
    unsigned short* qbf     = (unsigned short*)(ws + 131072);     //  25,165,824
    unsigned short* fbf     = (unsigned short*)(ws + 25296896);   //  56,623,104
    unsigned short* val_bf  = (unsigned short*)(ws + 81920000);   //  56,623,104 (B,H,S,D)
    float*          offattn = (float*)(ws + 163708928);           //   8,388,608
    unsigned short* Wv_t    = (unsigned short*)(ws + 172097536);  //   1,179,648
    unsigned short* Wo_t    = (unsigned short*)(ws + 173277184);  //   1,179,648
    unsigned short* Wqc_t   = (unsigned short*)(ws + 174456832);  //     196,608
    float*          bcat    = (float*)(ws + 174653440);           //         512

    // 1. prep: LN (query+feat) + both weight transposes + wqc concat
    prep_kernel<<<NLNB + NTRB + 384, 256, 0, stream>>>(
        query, feat, ln_q_w, ln_q_b, ln_f_w, ln_f_b, qbf, fbf, q_stats,
        W_val, W_out, Wv_t, Wo_t, W_off, W_attn, b_off, b_attn, Wqc_t, bcat);

    // 2. fat GEMM: value (256^2, 432 blocks) + offsets (128^2, 128 tail blocks)
    mfma_gemm256<<<NVALB + 128, 512, 0, stream>>>(
        fbf, Wv_t, b_val, val_bf, qbf, Wqc_t, bcat, offattn);

    // 3. fused msda + out-proj + final residual (256 blocks, 1/CU)
    msda_oproj_kernel<<<MQ / OROWS, 512, 0, stream>>>(
        val_bf, offattn, refp, Wo_t, b_out, query, q_stats, ln_q_w, ln_q_b,
        gamma, out);
}